// Round 2
// 426.923 us; speedup vs baseline: 1.0075x; 1.0075x over previous
//
#include <hip/hip_runtime.h>
#include <cstdint>
#include <cstddef>

#define NN   8192
#define DIN  256
#define DOUT 128
#define LRA  0.2f   // leaky-relu slope

// ---------------------------------------------------------------------------
// Kernel 1: h = input @ W   [8192x256]@[256x128] fp32
// block 256 threads -> 16 rows x 128 cols; k blocked by 4 (LDS float4 reads)
// ---------------------------------------------------------------------------
__global__ __launch_bounds__(256) void gemm_h_kernel(
    const float* __restrict__ input, const float* __restrict__ W,
    float* __restrict__ h)
{
    __shared__ float tile[16][DIN];  // 16 KB
    const int row0 = blockIdx.x * 16;
    {
        const float4* in4 = (const float4*)(input + (size_t)row0 * DIN);
        float4* t4 = (float4*)&tile[0][0];
        for (int k = threadIdx.x; k < 16 * DIN / 4; k += 256) t4[k] = in4[k];
    }
    __syncthreads();
    const int c = threadIdx.x & 127;
    const int g = threadIdx.x >> 7;       // 0..1 (wave-uniform)
    float acc[8] = {0.f, 0.f, 0.f, 0.f, 0.f, 0.f, 0.f, 0.f};
    #pragma unroll 2
    for (int k = 0; k < DIN; k += 4) {
        const float w0 = W[(k + 0) * DOUT + c];
        const float w1 = W[(k + 1) * DOUT + c];
        const float w2 = W[(k + 2) * DOUT + c];
        const float w3 = W[(k + 3) * DOUT + c];
        #pragma unroll
        for (int m = 0; m < 8; ++m) {
            const float4 av = *(const float4*)&tile[g * 8 + m][k];
            acc[m] += av.x * w0 + av.y * w1 + av.z * w2 + av.w * w3;
        }
    }
    #pragma unroll
    for (int m = 0; m < 8; ++m)
        h[(size_t)(row0 + g * 8 + m) * DOUT + c] = acc[m];
}

// ---------------------------------------------------------------------------
// Kernel 2: s[i] = h[i,:]@a_self, t[i] = h[i,:]@a_neighs  (one wave per row)
// ---------------------------------------------------------------------------
__global__ __launch_bounds__(256) void attn_vec_kernel(
    const float* __restrict__ h, const float* __restrict__ a_self,
    const float* __restrict__ a_neighs, float* __restrict__ s,
    float* __restrict__ t)
{
    const int wid  = (blockIdx.x * 256 + threadIdx.x) >> 6;
    const int lane = threadIdx.x & 63;
    if (wid >= NN) return;
    const float h0 = h[(size_t)wid * DOUT + lane];
    const float h1 = h[(size_t)wid * DOUT + 64 + lane];
    float vs = h0 * a_self[lane]   + h1 * a_self[64 + lane];
    float vn = h0 * a_neighs[lane] + h1 * a_neighs[64 + lane];
    for (int off = 32; off > 0; off >>= 1) {
        vs += __shfl_down(vs, off);
        vn += __shfl_down(vn, off);
    }
    if (lane == 0) { s[wid] = vs; t[wid] = vn; }
}

// ---------------------------------------------------------------------------
// Kernel 3: descending rank-sort of t by counting (order[rank] = j).
// block 256 = 32 j's x 8 segments of 1024; stable tie-break by index.
// float4-vectorized counting loop.
// ---------------------------------------------------------------------------
__global__ __launch_bounds__(256) void rank_kernel(
    const float* __restrict__ t, int* __restrict__ order)
{
    __shared__ float tl[NN];        // 32 KB
    __shared__ int   part[8][32];
    for (int k = threadIdx.x; k < NN; k += 256) tl[k] = t[k];
    __syncthreads();
    const int jloc = threadIdx.x & 31;
    const int seg  = threadIdx.x >> 5;
    const int j    = blockIdx.x * 32 + jloc;
    const float tj = tl[j];
    int r = 0;
    const int k0 = seg * (NN / 8);
    const float4* tl4 = (const float4*)(tl + k0);
    #pragma unroll 4
    for (int k = 0; k < NN / 8 / 4; ++k) {
        const float4 tv = tl4[k];
        const int kb = k0 + 4 * k;
        r += (tv.x > tj) ? 1 : ((tv.x == tj && (kb + 0) < j) ? 1 : 0);
        r += (tv.y > tj) ? 1 : ((tv.y == tj && (kb + 1) < j) ? 1 : 0);
        r += (tv.z > tj) ? 1 : ((tv.z == tj && (kb + 2) < j) ? 1 : 0);
        r += (tv.w > tj) ? 1 : ((tv.w == tj && (kb + 3) < j) ? 1 : 0);
    }
    part[seg][jloc] = r;
    __syncthreads();
    if (threadIdx.x < 32) {
        int rr = 0;
        #pragma unroll
        for (int ss = 0; ss < 8; ++ss) rr += part[ss][threadIdx.x];
        order[rr] = blockIdx.x * 32 + threadIdx.x;
    }
}

// ---------------------------------------------------------------------------
// Kernel 4: fused masked-softmax denominator + top-(action+1) threshold
// selection (via sorted-t walk) + sparse attention@h + ELU. One block per row.
// v2: no 32KB t staging (t read from L2), shfl reduction (2 barriers),
// top-256 of order + its t-values staged in LDS (gathered from L2),
// 2-deep pipelined h-gather. LDS ~3.3 KB -> occupancy no longer LDS-bound.
// Workspace footprint identical to the verified baseline (no tsorted array).
// ---------------------------------------------------------------------------
__global__ __launch_bounds__(256) void gat_row_kernel(
    const int* __restrict__ adj, const float* __restrict__ s_arr,
    const float* __restrict__ t_arr, const int* __restrict__ order,
    const int* __restrict__ action, const float* __restrict__ h,
    const int* __restrict__ policy, float* __restrict__ out)
{
    __shared__ int   ord_s[256];
    __shared__ float ts_s[256];
    __shared__ float red4[4];
    __shared__ float numlds[2][128];
    __shared__ int   sel_j[64];
    __shared__ float sel_w[64];
    __shared__ int   sel_cnt_sh;
    __shared__ int   done_sh;

    const int row = blockIdx.x;
    const int tid = threadIdx.x;

    // stage the head of the sorted order (covers the walk in ~all rows);
    // each thread writes its own slot from its own register -> no barrier
    // needed between the two stores.
    {
        const int oj = order[tid];
        ord_s[tid] = oj;
        ts_s[tid]  = t_arr[oj];
    }
    __syncthreads();

    const float s    = s_arr[row];
    const float tmax = ts_s[0];                      // global max t
    const float zc   = s + tmax;
    const float C    = fmaxf(zc, LRA * zc);          // lrelu(s + tmax) >= all e

    // ---- phase 1: denominator l = sum over valid j of exp(e_ij - C) ----
    const int4*   arow = (const int4*)(adj + (size_t)row * NN);
    const float4* t4   = (const float4*)t_arr;       // L2-resident, read once
    float acc = 0.f;
    #pragma unroll
    for (int k = 0; k < 8; ++k) {
        const int idx = tid + k * 256;
        const int4   a  = arow[idx];
        const float4 tv = t4[idx];
        float z, e, w;
        z = s + tv.x; e = fmaxf(z, LRA * z); w = __expf(e - C); if (a.x > 0) acc += w;
        z = s + tv.y; e = fmaxf(z, LRA * z); w = __expf(e - C); if (a.y > 0) acc += w;
        z = s + tv.z; e = fmaxf(z, LRA * z); w = __expf(e - C); if (a.z > 0) acc += w;
        z = s + tv.w; e = fmaxf(z, LRA * z); w = __expf(e - C); if (a.w > 0) acc += w;
    }
    // wave shfl reduction, then 4-way LDS combine (1 barrier)
    #pragma unroll
    for (int off = 32; off > 0; off >>= 1) acc += __shfl_down(acc, off);
    if ((tid & 63) == 0) red4[tid >> 6] = acc;
    __syncthreads();
    const float l = red4[0] + red4[1] + red4[2] + red4[3];

    // ---- phase 2: walk sorted-t order, select valid j with t >= t_thr ----
    int K = action[row] + 1;                 // keep (action+1)-th largest & above
    if (policy[0] == 0) K = 0x7FFFFFFF;      // breadth_policy==0: keep all valid
    const int c = tid & 127;
    const int g = tid >> 7;
    float accv = 0.f, accv2 = 0.f;

    const int lane = tid & 63;
    float tthr = -3.0e38f;   // wave-0 state (uniform across its lanes)
    int found = 0;
    int cnt = 0;
    int base = 0;

    while (true) {
        if (tid < 64) {
            const int p = base + lane;
            int j = 0, valid = 0;
            float tj = -3.0e38f;
            if (p < NN) {
                if (p < 256) { j = ord_s[p]; tj = ts_s[p]; }
                else         { j = order[p]; tj = t_arr[j]; }
                valid = (adj[(size_t)row * NN + j] > 0) ? 1 : 0;
            }
            const unsigned long long vm = __ballot(valid);
            if (!found) {
                const int cv = __popcll(vm);
                if (cnt + cv >= K) {
                    const int need = K - cnt;
                    const int myrank =
                        __popcll(vm & ((1ull << lane) - 1ull)) + 1;
                    const unsigned long long pm =
                        __ballot(valid && (myrank == need));
                    const int L = __ffsll((long long)pm) - 1;
                    tthr  = __shfl(tj, L);
                    found = 1;
                } else {
                    cnt += cv;
                }
            }
            const int selected = valid && (tj >= tthr);
            const unsigned long long sm = __ballot(selected);
            const int pos = __popcll(sm & ((1ull << lane) - 1ull));
            if (selected) {
                const float z = s + tj;
                const float e = fmaxf(z, LRA * z);
                sel_j[pos] = j;
                sel_w[pos] = __expf(e - C);
            }
            if (lane == 0) {
                sel_cnt_sh = __popcll(sm);
                const int nb = base + 64;
                int dn;
                if (nb >= NN) dn = 1;
                else if (found) {
                    const float tnb = (nb < 256) ? ts_s[nb] : t_arr[order[nb]];
                    dn = (tnb < tthr) ? 1 : 0;
                } else dn = 0;
                done_sh = dn;
            }
        }
        __syncthreads();
        const int nsel = sel_cnt_sh;
        const int dn   = done_sh;
        // 2-deep pipelined sparse gather: two h-loads in flight
        for (int e2 = g; e2 < nsel; e2 += 4) {
            const float w0 = sel_w[e2];
            const float v0 = h[(size_t)sel_j[e2] * DOUT + c];
            if (e2 + 2 < nsel) {
                accv2 += sel_w[e2 + 2] * h[(size_t)sel_j[e2 + 2] * DOUT + c];
            }
            accv += w0 * v0;
        }
        base += 64;
        if (dn) break;
        __syncthreads();
    }
    accv += accv2;

    numlds[g][c] = accv;
    __syncthreads();
    if (tid < 128) {
        const float v = (numlds[0][tid] + numlds[1][tid]) / l;
        out[(size_t)row * DOUT + tid] = (v > 0.f) ? v : expm1f(v);
    }
}

// ---------------------------------------------------------------------------
extern "C" void kernel_launch(void* const* d_in, const int* in_sizes, int n_in,
                              void* d_out, int out_size, void* d_ws,
                              size_t ws_size, hipStream_t stream)
{
    const float* input    = (const float*)d_in[0];
    const int*   adj      = (const int*)d_in[1];
    const int*   action   = (const int*)d_in[2];
    const float* W        = (const float*)d_in[3];
    const float* a_self   = (const float*)d_in[4];
    const float* a_neighs = (const float*)d_in[5];
    const int*   policy   = (const int*)d_in[6];
    float* out = (float*)d_out;

    float* ws    = (float*)d_ws;
    float* h     = ws;                         // 8192*128 fp32 = 4 MB
    float* s     = ws + (size_t)NN * DOUT;     // 8192 fp32
    float* t     = s + NN;                     // 8192 fp32
    int*   order = (int*)(t + NN);             // 8192 int32

    hipLaunchKernelGGL(gemm_h_kernel, dim3(512), dim3(256), 0, stream,
                       input, W, h);
    hipLaunchKernelGGL(attn_vec_kernel, dim3(2048), dim3(256), 0, stream,
                       h, a_self, a_neighs, s, t);
    hipLaunchKernelGGL(rank_kernel, dim3(256), dim3(256), 0, stream,
                       t, order);
    hipLaunchKernelGGL(gat_row_kernel, dim3(8192), dim3(256), 0, stream,
                       adj, s, t, order, action, h, policy, out);
}